// Round 4
// baseline (189.722 us; speedup 1.0000x reference)
//
#include <hip/hip_runtime.h>
#include <hip/hip_bf16.h>

// Problem constants
#define VD 160           // vol D=H=W
#define OD 128           // output crop size
#define CROP0 16         // (160-128)/2
#define FSZ 11           // cropped field size
#define RAWSZ 15         // raw field size
#define NBATCH 4
#define ODQ 4            // outputs per thread along od

// ---------------------------------------------------------------------------
// Kernel 1: field prep (blocks 0..2) + Rodrigues/theta (block 3).
// ---------------------------------------------------------------------------
__global__ __launch_bounds__(256) void prep_kernel(
        const float* __restrict__ rot, const float* __restrict__ scale,
        const float* __restrict__ shift,
        const float* __restrict__ dz, const float* __restrict__ dy,
        const float* __restrict__ dx,
        float* __restrict__ theta, float* __restrict__ fields) {
    const int tid = threadIdx.x;
    const int chan = blockIdx.x;

    if (chan == 3) {
        int n = tid;
        if (n >= NBATCH) return;
        float rx = rot[n*3+0], ry = rot[n*3+1], rz = rot[n*3+2];
        float t2 = rx*rx + ry*ry + rz*rz;
        const float eps = 1e-6f;
        float th = sqrtf(fmaxf(t2, eps));
        float inv = 1.0f / (th + eps);
        float wx = rx*inv, wy = ry*inv, wz = rz*inv;
        float c = cosf(th), s = sinf(th), k = 1.0f - c;
        float R[9];
        if (t2 > eps) {
            R[0] = c + wx*wx*k;      R[1] = wx*wy*k - wz*s;  R[2] = wy*s + wx*wz*k;
            R[3] = wz*s + wx*wy*k;   R[4] = c + wy*wy*k;     R[5] = -wx*s + wy*wz*k;
            R[6] = -wy*s + wx*wz*k;  R[7] = wx*s + wy*wz*k;  R[8] = c + wz*wz*k;
        } else {
            R[0] = 1.0f; R[1] = -rz;  R[2] = ry;
            R[3] = rz;   R[4] = 1.0f; R[5] = -rx;
            R[6] = -ry;  R[7] = rx;   R[8] = 1.0f;
        }
        for (int i = 0; i < 3; ++i) {
            for (int j = 0; j < 3; ++j)
                theta[n*12 + i*4 + j] = R[i*3 + j] * scale[n*3 + j];
            theta[n*12 + i*4 + 3] = shift[n*3 + i];
        }
        return;
    }

    __shared__ float bufA[RAWSZ*RAWSZ*RAWSZ];
    __shared__ float bufB[RAWSZ*RAWSZ*RAWSZ];
    const float* raw = (chan == 0) ? dz : (chan == 1) ? dy : dx;
    const int NTOT = RAWSZ*RAWSZ*RAWSZ;   // 3375

    for (int i = tid; i < NTOT; i += 256)
        bufA[i] = (raw[i] - 0.5f) * 4.0f;
    __syncthreads();

    float* src = bufA;
    float* dst = bufB;
    for (int it = 0; it < 4; ++it) {
        for (int ax = 0; ax < 3; ++ax) {
            const int stride = (ax == 0) ? RAWSZ*RAWSZ : (ax == 1) ? RAWSZ : 1;
            for (int i = tid; i < NTOT; i += 256) {
                int z = i / (RAWSZ*RAWSZ);
                int r = i % (RAWSZ*RAWSZ);
                int y = r / RAWSZ;
                int x = r % RAWSZ;
                int c = (ax == 0) ? z : (ax == 1) ? y : x;
                float s = 0.0f;
                #pragma unroll
                for (int t = -2; t <= 2; ++t) {
                    int cc = min(max(c + t, 0), RAWSZ - 1);
                    s += src[i + (cc - c) * stride];
                }
                dst[i] = s * 0.2f;
            }
            __syncthreads();
            float* tmp = src; src = dst; dst = tmp;
        }
    }
    for (int i = tid; i < FSZ*FSZ*FSZ; i += 256) {
        int z = i / (FSZ*FSZ);
        int r = i % (FSZ*FSZ);
        int y = r / FSZ;
        int x = r % FSZ;
        fields[chan*FSZ*FSZ*FSZ + i] =
            src[(z+2)*RAWSZ*RAWSZ + (y+2)*RAWSZ + (x+2)];
    }
}

// ---------------------------------------------------------------------------
// resize helper: src = (m+0.5)*(11/160) - 0.5, clipped to [0,10]
// ---------------------------------------------------------------------------
__device__ __forceinline__ void resize_coord(int m, int& i0, int& i1, float& w) {
    float s = fmaf((float)m + 0.5f, (float)FSZ / (float)VD, -0.5f);
    s = fminf(fmaxf(s, 0.0f), (float)(FSZ - 1));
    float f = floorf(s);
    i0 = (int)f;
    i1 = min(i0 + 1, FSZ - 1);
    w = s - f;
}

// ---------------------------------------------------------------------------
// Kernel 2: main sampler. Block = 512 threads covering (ow=128, oh=2, od=8);
// each thread computes ODQ=4 consecutive od outputs. All 32 vol loads are
// forced to issue back-to-back (sched_barrier keeps the blend VALU below
// them) so one wave has 32 loads in flight -> single latency exposure.
// grid = (OD/2, OD/8, NBATCH).
// ---------------------------------------------------------------------------
__global__ __launch_bounds__(512) void sample_kernel(
        const float* __restrict__ vol, const float* __restrict__ theta,
        const float* __restrict__ fields, float* __restrict__ out) {
    __shared__ float e[2][8][3][12];

    const int tid  = threadIdx.x;
    const int ow   = tid & 127;
    const int oh_i = (tid >> 7) & 1;
    const int odq  = tid >> 8;            // 0..1
    const int oh   = (blockIdx.x << 1) | oh_i;
    const int od0  = (blockIdx.y << 3) | (odq << 2);   // first of 4 od
    const int n    = blockIdx.z;

    // ---- fill e: 2*8*3*11 = 528 items ----
    for (int t = tid; t < 528; t += 512) {
        int q = t;
        int eoh = q / 264;  q -= eoh * 264;
        int eod = q / 33;   q -= eod * 33;
        int c   = q / 11;
        int xi  = q - c * 11;
        int d_ = (blockIdx.y << 3) + eod + CROP0;
        int h_ = ((blockIdx.x << 1) | eoh) + CROP0;
        int zi0, zi1, yi0, yi1;
        float zw, yw;
        resize_coord(d_, zi0, zi1, zw);
        resize_coord(h_, yi0, yi1, yw);
        const float* f = fields + c * (FSZ*FSZ*FSZ);
        float v = f[zi0*121 + yi0*11 + xi] * ((1.0f-zw)*(1.0f-yw))
                + f[zi0*121 + yi1*11 + xi] * ((1.0f-zw)*yw)
                + f[zi1*121 + yi0*11 + xi] * (zw*(1.0f-yw))
                + f[zi1*121 + yi1*11 + xi] * (zw*yw);
        e[eoh][eod][c][xi] = v * 80.0f;   // pre-scaled to voxel units
    }
    __syncthreads();

    const int w_ = ow + CROP0;
    const int h_ = oh + CROP0;

    const float x = fmaf(2.0f * (float)w_ + 1.0f, 1.0f / (float)VD, -1.0f);
    const float y = fmaf(2.0f * (float)h_ + 1.0f, 1.0f / (float)VD, -1.0f);

    // x-knot lerp params (shared by all 4 outputs)
    int xi0, xi1; float xw;
    resize_coord(w_, xi0, xi1, xw);

    const float* th = theta + n*12;
    const float cx = fmaf(th[0]*x + th[1]*y + th[3], 80.0f, 79.5f);
    const float cy = fmaf(th[4]*x + th[5]*y + th[7], 80.0f, 79.5f);
    const float cz = fmaf(th[8]*x + th[9]*y + th[11], 80.0f, 79.5f);
    const float tz0 = th[2] * 80.0f, tz1 = th[6] * 80.0f, tz2 = th[10] * 80.0f;

    const float* v = vol + (size_t)n * (VD*VD*VD);

    int   off[ODQ][4];
    int   xA[ODQ], xB[ODQ];
    float WX0[ODQ], WX1[ODQ], WY0[ODQ], WY1[ODQ], WZ0[ODQ], WZ1[ODQ];

    #pragma unroll
    for (int k = 0; k < ODQ; ++k) {
        const int od = od0 + k;
        const int d_ = od + CROP0;
        const float z = fmaf(2.0f * (float)d_ + 1.0f, 1.0f / (float)VD, -1.0f);
        const float* ek = &e[oh_i][(odq << 2) + k][0][0];
        const float d80x = ek[      xi0] + (ek[      xi1] - ek[      xi0]) * xw;
        const float d80y = ek[12  + xi0] + (ek[12  + xi1] - ek[12  + xi0]) * xw;
        const float d80z = ek[24  + xi0] + (ek[24  + xi1] - ek[24  + xi0]) * xw;

        const float xs = fmaf(tz0, z, cx) + d80x;
        const float ys = fmaf(tz1, z, cy) + d80y;
        const float zs = fmaf(tz2, z, cz) + d80z;

        const float x0f = floorf(xs), y0f = floorf(ys), z0f = floorf(zs);
        const float fx = xs - x0f, fy = ys - y0f, fz = zs - z0f;
        const int ix0 = (int)x0f, iy0 = (int)y0f, iz0 = (int)z0f;
        const int ix1 = ix0 + 1,  iy1 = iy0 + 1,  iz1 = iz0 + 1;

        WX0[k] = ((unsigned)ix0 < (unsigned)VD) ? (1.0f - fx) : 0.0f;
        WX1[k] = ((unsigned)ix1 < (unsigned)VD) ? fx          : 0.0f;
        WY0[k] = ((unsigned)iy0 < (unsigned)VD) ? (1.0f - fy) : 0.0f;
        WY1[k] = ((unsigned)iy1 < (unsigned)VD) ? fy          : 0.0f;
        WZ0[k] = ((unsigned)iz0 < (unsigned)VD) ? (1.0f - fz) : 0.0f;
        WZ1[k] = ((unsigned)iz1 < (unsigned)VD) ? fz          : 0.0f;

        const int xc0 = min(max(ix0, 0), VD-1), xc1 = min(max(ix1, 0), VD-1);
        const int yc0 = min(max(iy0, 0), VD-1), yc1 = min(max(iy1, 0), VD-1);
        const int zc0 = min(max(iz0, 0), VD-1), zc1 = min(max(iz1, 0), VD-1);

        off[k][0] = (zc0*VD + yc0)*VD;
        off[k][1] = (zc0*VD + yc1)*VD;
        off[k][2] = (zc1*VD + yc0)*VD;
        off[k][3] = (zc1*VD + yc1)*VD;
        xA[k] = xc0; xB[k] = xc1;
    }

    // issue all 32 loads back-to-back
    float t00a[ODQ], t00b[ODQ], t01a[ODQ], t01b[ODQ];
    float t10a[ODQ], t10b[ODQ], t11a[ODQ], t11b[ODQ];
    #pragma unroll
    for (int k = 0; k < ODQ; ++k) {
        t00a[k] = v[off[k][0] + xA[k]];  t00b[k] = v[off[k][0] + xB[k]];
        t01a[k] = v[off[k][1] + xA[k]];  t01b[k] = v[off[k][1] + xB[k]];
        t10a[k] = v[off[k][2] + xA[k]];  t10b[k] = v[off[k][2] + xB[k]];
        t11a[k] = v[off[k][3] + xA[k]];  t11b[k] = v[off[k][3] + xB[k]];
    }
    // Scheduler fence: nothing below may be hoisted above this point, so the
    // 32 loads above issue as one cluster and drain with progressive vmcnt.
    __builtin_amdgcn_sched_barrier(0);

    #pragma unroll
    for (int k = 0; k < ODQ; ++k) {
        const float r00 = t00a[k]*WX0[k] + t00b[k]*WX1[k];
        const float r01 = t01a[k]*WX0[k] + t01b[k]*WX1[k];
        const float r10 = t10a[k]*WX0[k] + t10b[k]*WX1[k];
        const float r11 = t11a[k]*WX0[k] + t11b[k]*WX1[k];
        const float r = (r00*WY0[k] + r01*WY1[k])*WZ0[k]
                      + (r10*WY0[k] + r11*WY1[k])*WZ1[k];
        const int od = od0 + k;
        __builtin_nontemporal_store(
            r, &out[(((size_t)n*OD + od)*OD + oh)*OD + ow]);
    }
}

// ---------------------------------------------------------------------------
extern "C" void kernel_launch(void* const* d_in, const int* in_sizes, int n_in,
                              void* d_out, int out_size, void* d_ws, size_t ws_size,
                              hipStream_t stream) {
    const float* vol   = (const float*)d_in[0];
    const float* rot   = (const float*)d_in[1];
    const float* scale = (const float*)d_in[2];
    const float* shift = (const float*)d_in[3];
    const float* dz    = (const float*)d_in[4];
    const float* dy    = (const float*)d_in[5];
    const float* dx    = (const float*)d_in[6];
    float* out = (float*)d_out;

    float* ws     = (float*)d_ws;
    float* theta  = ws;         // 4*12 = 48 floats
    float* fields = ws + 48;    // 3*1331 floats

    prep_kernel<<<4, 256, 0, stream>>>(rot, scale, shift, dz, dy, dx,
                                       theta, fields);
    dim3 grid(OD/2, OD/8, NBATCH);
    sample_kernel<<<grid, 512, 0, stream>>>(vol, theta, fields, out);
}

// Round 5
// 176.283 us; speedup vs baseline: 1.0762x; 1.0762x over previous
//
#include <hip/hip_runtime.h>
#include <hip/hip_bf16.h>

// Problem constants
#define VD 160           // vol D=H=W
#define OD 128           // output crop size
#define CROP0 16         // (160-128)/2
#define FSZ 11           // cropped field size
#define RAWSZ 15         // raw field size
#define NBATCH 4
#define ODQ 2            // outputs per thread along od

// ---------------------------------------------------------------------------
// Kernel 1: field prep (blocks 0..2) + Rodrigues/theta (block 3).
// ---------------------------------------------------------------------------
__global__ __launch_bounds__(256) void prep_kernel(
        const float* __restrict__ rot, const float* __restrict__ scale,
        const float* __restrict__ shift,
        const float* __restrict__ dz, const float* __restrict__ dy,
        const float* __restrict__ dx,
        float* __restrict__ theta, float* __restrict__ fields) {
    const int tid = threadIdx.x;
    const int chan = blockIdx.x;

    if (chan == 3) {
        int n = tid;
        if (n >= NBATCH) return;
        float rx = rot[n*3+0], ry = rot[n*3+1], rz = rot[n*3+2];
        float t2 = rx*rx + ry*ry + rz*rz;
        const float eps = 1e-6f;
        float th = sqrtf(fmaxf(t2, eps));
        float inv = 1.0f / (th + eps);
        float wx = rx*inv, wy = ry*inv, wz = rz*inv;
        float c = cosf(th), s = sinf(th), k = 1.0f - c;
        float R[9];
        if (t2 > eps) {
            R[0] = c + wx*wx*k;      R[1] = wx*wy*k - wz*s;  R[2] = wy*s + wx*wz*k;
            R[3] = wz*s + wx*wy*k;   R[4] = c + wy*wy*k;     R[5] = -wx*s + wy*wz*k;
            R[6] = -wy*s + wx*wz*k;  R[7] = wx*s + wy*wz*k;  R[8] = c + wz*wz*k;
        } else {
            R[0] = 1.0f; R[1] = -rz;  R[2] = ry;
            R[3] = rz;   R[4] = 1.0f; R[5] = -rx;
            R[6] = -ry;  R[7] = rx;   R[8] = 1.0f;
        }
        for (int i = 0; i < 3; ++i) {
            for (int j = 0; j < 3; ++j)
                theta[n*12 + i*4 + j] = R[i*3 + j] * scale[n*3 + j];
            theta[n*12 + i*4 + 3] = shift[n*3 + i];
        }
        return;
    }

    __shared__ float bufA[RAWSZ*RAWSZ*RAWSZ];
    __shared__ float bufB[RAWSZ*RAWSZ*RAWSZ];
    const float* raw = (chan == 0) ? dz : (chan == 1) ? dy : dx;
    const int NTOT = RAWSZ*RAWSZ*RAWSZ;   // 3375

    for (int i = tid; i < NTOT; i += 256)
        bufA[i] = (raw[i] - 0.5f) * 4.0f;
    __syncthreads();

    float* src = bufA;
    float* dst = bufB;
    for (int it = 0; it < 4; ++it) {
        for (int ax = 0; ax < 3; ++ax) {
            const int stride = (ax == 0) ? RAWSZ*RAWSZ : (ax == 1) ? RAWSZ : 1;
            for (int i = tid; i < NTOT; i += 256) {
                int z = i / (RAWSZ*RAWSZ);
                int r = i % (RAWSZ*RAWSZ);
                int y = r / RAWSZ;
                int x = r % RAWSZ;
                int c = (ax == 0) ? z : (ax == 1) ? y : x;
                float s = 0.0f;
                #pragma unroll
                for (int t = -2; t <= 2; ++t) {
                    int cc = min(max(c + t, 0), RAWSZ - 1);
                    s += src[i + (cc - c) * stride];
                }
                dst[i] = s * 0.2f;
            }
            __syncthreads();
            float* tmp = src; src = dst; dst = tmp;
        }
    }
    for (int i = tid; i < FSZ*FSZ*FSZ; i += 256) {
        int z = i / (FSZ*FSZ);
        int r = i % (FSZ*FSZ);
        int y = r / FSZ;
        int x = r % FSZ;
        fields[chan*FSZ*FSZ*FSZ + i] =
            src[(z+2)*RAWSZ*RAWSZ + (y+2)*RAWSZ + (x+2)];
    }
}

// ---------------------------------------------------------------------------
// resize helper: src = (m+0.5)*(11/160) - 0.5, clipped to [0,10]
// ---------------------------------------------------------------------------
__device__ __forceinline__ void resize_coord(int m, int& i0, int& i1, float& w) {
    float s = fmaf((float)m + 0.5f, (float)FSZ / (float)VD, -0.5f);
    s = fminf(fmaxf(s, 0.0f), (float)(FSZ - 1));
    float f = floorf(s);
    i0 = (int)f;
    i1 = min(i0 + 1, FSZ - 1);
    w = s - f;
}

// ---------------------------------------------------------------------------
// Kernel 2: main sampler.
// Wave lane map = 16(ow) x 4(oh) patch  -> minimizes distinct cache lines
// per vector-memory instruction under rotation (TA-throughput bound).
// Block = 512 threads = 8 waves arranged 2(wx) x 2(wh) x 2(wd);
// block output tile = 32(w) x 8(h) x 4(d), each thread does ODQ=2 od's.
// Both x-taps of a row are fetched with ONE dwordx2 load (base=min(xc0,158));
// x-selection is folded into per-row weights wA/wB.
// grid = (OD/32, OD/8, (OD/4)*NBATCH).
// ---------------------------------------------------------------------------
__global__ __launch_bounds__(512) void sample_kernel(
        const float* __restrict__ vol, const float* __restrict__ theta,
        const float* __restrict__ fields, float* __restrict__ out) {
    __shared__ float e[8][4][3][12];   // [oh_l][od_l][chan][xi]

    const int tid  = threadIdx.x;
    const int lane = tid & 63;
    const int wl   = lane & 15;        // x within wave patch
    const int hl   = lane >> 4;        // y within wave patch (0..3)
    const int wv   = tid >> 6;         // wave id 0..7
    const int wx   = wv & 1;
    const int wh   = (wv >> 1) & 1;
    const int wd   = wv >> 2;          // 0..1

    const int ow_l = (wx << 4) | wl;       // 0..31
    const int oh_l = (wh << 2) | hl;       // 0..7
    const int ow   = (blockIdx.x << 5) | ow_l;
    const int oh   = (blockIdx.y << 3) | oh_l;
    const int odb  = (blockIdx.z & 31) << 2;   // od block base (0..124)
    const int n    = blockIdx.z >> 5;

    // ---- fill e: 8*4*3*11 = 1056 items ----
    for (int t = tid; t < 1056; t += 512) {
        int q = t;
        int eoh = q / 132;  q -= eoh * 132;
        int eod = q / 33;   q -= eod * 33;
        int c   = q / 11;
        int xi  = q - c * 11;
        int d_ = odb + eod + CROP0;
        int h_ = (blockIdx.y << 3) + eoh + CROP0;
        int zi0, zi1, yi0, yi1;
        float zw, yw;
        resize_coord(d_, zi0, zi1, zw);
        resize_coord(h_, yi0, yi1, yw);
        const float* f = fields + c * (FSZ*FSZ*FSZ);
        float v = f[zi0*121 + yi0*11 + xi] * ((1.0f-zw)*(1.0f-yw))
                + f[zi0*121 + yi1*11 + xi] * ((1.0f-zw)*yw)
                + f[zi1*121 + yi0*11 + xi] * (zw*(1.0f-yw))
                + f[zi1*121 + yi1*11 + xi] * (zw*yw);
        e[eoh][eod][c][xi] = v * 80.0f;   // pre-scaled to voxel units
    }
    __syncthreads();

    const int w_ = ow + CROP0;
    const int h_ = oh + CROP0;

    const float x = fmaf(2.0f * (float)w_ + 1.0f, 1.0f / (float)VD, -1.0f);
    const float y = fmaf(2.0f * (float)h_ + 1.0f, 1.0f / (float)VD, -1.0f);

    int xi0, xi1; float xw;
    resize_coord(w_, xi0, xi1, xw);

    const float* th = theta + n*12;
    const float cx = fmaf(th[0]*x + th[1]*y + th[3], 80.0f, 79.5f);
    const float cy = fmaf(th[4]*x + th[5]*y + th[7], 80.0f, 79.5f);
    const float cz = fmaf(th[8]*x + th[9]*y + th[11], 80.0f, 79.5f);
    const float tz0 = th[2] * 80.0f, tz1 = th[6] * 80.0f, tz2 = th[10] * 80.0f;

    const float* v = vol + (size_t)n * (VD*VD*VD);

    int   base00[ODQ], base01[ODQ], base10[ODQ], base11[ODQ];
    float wA[ODQ], wB[ODQ];
    float WY0[ODQ], WY1[ODQ], WZ0[ODQ], WZ1[ODQ];

    #pragma unroll
    for (int k = 0; k < ODQ; ++k) {
        const int od_l = (wd << 1) | k;
        const int od = odb + od_l;
        const int d_ = od + CROP0;
        const float z = fmaf(2.0f * (float)d_ + 1.0f, 1.0f / (float)VD, -1.0f);
        const float* ek = &e[oh_l][od_l][0][0];
        const float d80x = ek[      xi0] + (ek[      xi1] - ek[      xi0]) * xw;
        const float d80y = ek[12  + xi0] + (ek[12  + xi1] - ek[12  + xi0]) * xw;
        const float d80z = ek[24  + xi0] + (ek[24  + xi1] - ek[24  + xi0]) * xw;

        const float xs = fmaf(tz0, z, cx) + d80x;
        const float ys = fmaf(tz1, z, cy) + d80y;
        const float zs = fmaf(tz2, z, cz) + d80z;

        const float x0f = floorf(xs), y0f = floorf(ys), z0f = floorf(zs);
        const float fx = xs - x0f, fy = ys - y0f, fz = zs - z0f;
        const int ix0 = (int)x0f, iy0 = (int)y0f, iz0 = (int)z0f;
        const int ix1 = ix0 + 1,  iy1 = iy0 + 1,  iz1 = iz0 + 1;

        const float WX0 = ((unsigned)ix0 < (unsigned)VD) ? (1.0f - fx) : 0.0f;
        const float WX1 = ((unsigned)ix1 < (unsigned)VD) ? fx          : 0.0f;
        WY0[k] = ((unsigned)iy0 < (unsigned)VD) ? (1.0f - fy) : 0.0f;
        WY1[k] = ((unsigned)iy1 < (unsigned)VD) ? fy          : 0.0f;
        WZ0[k] = ((unsigned)iz0 < (unsigned)VD) ? (1.0f - fz) : 0.0f;
        WZ1[k] = ((unsigned)iz1 < (unsigned)VD) ? fz          : 0.0f;

        const int xc0 = min(max(ix0, 0), VD-1), xc1 = min(max(ix1, 0), VD-1);
        const int yc0 = min(max(iy0, 0), VD-1), yc1 = min(max(iy1, 0), VD-1);
        const int zc0 = min(max(iz0, 0), VD-1), zc1 = min(max(iz1, 0), VD-1);

        // one dwordx2 covers [base, base+1]; xc0,xc1 are always within it
        const int base = min(xc0, VD-2);
        const bool hi0 = (xc0 != base);   // xc0 at base+1
        const bool hi1 = (xc1 != base);   // xc1 at base+1
        wA[k] = (hi0 ? 0.0f : WX0) + (hi1 ? 0.0f : WX1);
        wB[k] = (hi0 ? WX0 : 0.0f) + (hi1 ? WX1 : 0.0f);

        base00[k] = (zc0*VD + yc0)*VD + base;
        base01[k] = (zc0*VD + yc1)*VD + base;
        base10[k] = (zc1*VD + yc0)*VD + base;
        base11[k] = (zc1*VD + yc1)*VD + base;
    }

    // 8 paired loads (4 rows x ODQ) issued together
    float2 p00[ODQ], p01[ODQ], p10[ODQ], p11[ODQ];
    #pragma unroll
    for (int k = 0; k < ODQ; ++k) {
        __builtin_memcpy(&p00[k], v + base00[k], sizeof(float2));
        __builtin_memcpy(&p01[k], v + base01[k], sizeof(float2));
        __builtin_memcpy(&p10[k], v + base10[k], sizeof(float2));
        __builtin_memcpy(&p11[k], v + base11[k], sizeof(float2));
    }

    #pragma unroll
    for (int k = 0; k < ODQ; ++k) {
        const float r00 = p00[k].x*wA[k] + p00[k].y*wB[k];
        const float r01 = p01[k].x*wA[k] + p01[k].y*wB[k];
        const float r10 = p10[k].x*wA[k] + p10[k].y*wB[k];
        const float r11 = p11[k].x*wA[k] + p11[k].y*wB[k];
        const float r = (r00*WY0[k] + r01*WY1[k])*WZ0[k]
                      + (r10*WY0[k] + r11*WY1[k])*WZ1[k];
        const int od = odb + ((wd << 1) | k);
        __builtin_nontemporal_store(
            r, &out[(((size_t)n*OD + od)*OD + oh)*OD + ow]);
    }
}

// ---------------------------------------------------------------------------
extern "C" void kernel_launch(void* const* d_in, const int* in_sizes, int n_in,
                              void* d_out, int out_size, void* d_ws, size_t ws_size,
                              hipStream_t stream) {
    const float* vol   = (const float*)d_in[0];
    const float* rot   = (const float*)d_in[1];
    const float* scale = (const float*)d_in[2];
    const float* shift = (const float*)d_in[3];
    const float* dz    = (const float*)d_in[4];
    const float* dy    = (const float*)d_in[5];
    const float* dx    = (const float*)d_in[6];
    float* out = (float*)d_out;

    float* ws     = (float*)d_ws;
    float* theta  = ws;         // 4*12 = 48 floats
    float* fields = ws + 48;    // 3*1331 floats

    prep_kernel<<<4, 256, 0, stream>>>(rot, scale, shift, dz, dy, dx,
                                       theta, fields);
    dim3 grid(OD/32, OD/8, (OD/4)*NBATCH);
    sample_kernel<<<grid, 512, 0, stream>>>(vol, theta, fields, out);
}

// Round 6
// 160.510 us; speedup vs baseline: 1.1820x; 1.0983x over previous
//
#include <hip/hip_runtime.h>
#include <hip/hip_bf16.h>

// Problem constants
#define VD 160           // vol D=H=W
#define OD 128           // output crop size
#define CROP0 16         // (160-128)/2
#define FSZ 11           // cropped field size
#define RAWSZ 15         // raw field size
#define NBATCH 4
#define ODQ 4            // outputs per thread along od

// e-table layout: [c][oh_l][od_l][ESTR]; ESTR=17 -> oh stride 136 floats,
// banks for the 4 hl-groups = {0,8,16,24}: conflict-free.
#define ESTR 17
#define EOH  (8*ESTR)      // 136
#define ECH  (8*8*ESTR)    // 1088

// ---------------------------------------------------------------------------
// Kernel 1: field prep (blocks 0..2) + Rodrigues/theta (block 3).
// ---------------------------------------------------------------------------
__global__ __launch_bounds__(256) void prep_kernel(
        const float* __restrict__ rot, const float* __restrict__ scale,
        const float* __restrict__ shift,
        const float* __restrict__ dz, const float* __restrict__ dy,
        const float* __restrict__ dx,
        float* __restrict__ theta, float* __restrict__ fields) {
    const int tid = threadIdx.x;
    const int chan = blockIdx.x;

    if (chan == 3) {
        int n = tid;
        if (n >= NBATCH) return;
        float rx = rot[n*3+0], ry = rot[n*3+1], rz = rot[n*3+2];
        float t2 = rx*rx + ry*ry + rz*rz;
        const float eps = 1e-6f;
        float th = sqrtf(fmaxf(t2, eps));
        float inv = 1.0f / (th + eps);
        float wx = rx*inv, wy = ry*inv, wz = rz*inv;
        float c = cosf(th), s = sinf(th), k = 1.0f - c;
        float R[9];
        if (t2 > eps) {
            R[0] = c + wx*wx*k;      R[1] = wx*wy*k - wz*s;  R[2] = wy*s + wx*wz*k;
            R[3] = wz*s + wx*wy*k;   R[4] = c + wy*wy*k;     R[5] = -wx*s + wy*wz*k;
            R[6] = -wy*s + wx*wz*k;  R[7] = wx*s + wy*wz*k;  R[8] = c + wz*wz*k;
        } else {
            R[0] = 1.0f; R[1] = -rz;  R[2] = ry;
            R[3] = rz;   R[4] = 1.0f; R[5] = -rx;
            R[6] = -ry;  R[7] = rx;   R[8] = 1.0f;
        }
        for (int i = 0; i < 3; ++i) {
            for (int j = 0; j < 3; ++j)
                theta[n*12 + i*4 + j] = R[i*3 + j] * scale[n*3 + j];
            theta[n*12 + i*4 + 3] = shift[n*3 + i];
        }
        return;
    }

    __shared__ float bufA[RAWSZ*RAWSZ*RAWSZ];
    __shared__ float bufB[RAWSZ*RAWSZ*RAWSZ];
    const float* raw = (chan == 0) ? dz : (chan == 1) ? dy : dx;
    const int NTOT = RAWSZ*RAWSZ*RAWSZ;   // 3375

    for (int i = tid; i < NTOT; i += 256)
        bufA[i] = (raw[i] - 0.5f) * 4.0f;
    __syncthreads();

    float* src = bufA;
    float* dst = bufB;
    for (int it = 0; it < 4; ++it) {
        for (int ax = 0; ax < 3; ++ax) {
            const int stride = (ax == 0) ? RAWSZ*RAWSZ : (ax == 1) ? RAWSZ : 1;
            for (int i = tid; i < NTOT; i += 256) {
                int z = i / (RAWSZ*RAWSZ);
                int r = i % (RAWSZ*RAWSZ);
                int y = r / RAWSZ;
                int x = r % RAWSZ;
                int c = (ax == 0) ? z : (ax == 1) ? y : x;
                float s = 0.0f;
                #pragma unroll
                for (int t = -2; t <= 2; ++t) {
                    int cc = min(max(c + t, 0), RAWSZ - 1);
                    s += src[i + (cc - c) * stride];
                }
                dst[i] = s * 0.2f;
            }
            __syncthreads();
            float* tmp = src; src = dst; dst = tmp;
        }
    }
    for (int i = tid; i < FSZ*FSZ*FSZ; i += 256) {
        int z = i / (FSZ*FSZ);
        int r = i % (FSZ*FSZ);
        int y = r / FSZ;
        int x = r % FSZ;
        fields[chan*FSZ*FSZ*FSZ + i] =
            src[(z+2)*RAWSZ*RAWSZ + (y+2)*RAWSZ + (x+2)];
    }
}

// ---------------------------------------------------------------------------
// resize helper: src = (m+0.5)*(11/160) - 0.5, clipped to [0,10]
// ---------------------------------------------------------------------------
__device__ __forceinline__ void resize_coord(int m, int& i0, int& i1, float& w) {
    float s = fmaf((float)m + 0.5f, (float)FSZ / (float)VD, -0.5f);
    s = fminf(fmaxf(s, 0.0f), (float)(FSZ - 1));
    float f = floorf(s);
    i0 = (int)f;
    i1 = min(i0 + 1, FSZ - 1);
    w = s - f;
}

// ---------------------------------------------------------------------------
// Kernel 2: main sampler.
// Wave lane map = 16(ow) x 4(oh); block = 512 thr = 8 waves (2wx x 2wh x 2wd);
// block tile = 32(w) x 8(h) x 8(d); each thread does ODQ=4 od's.
// e[c][oh_l][od_l][17]: (z,y)-bilinear of disp at 11 x-knots, x80; padded so
// the 4 hl-groups are on distinct LDS banks; x-knot pair read via one vaddr
// + imm offsets (ds_read2-friendly; xi1 == xi0+1 always, xw=0 at top knot).
// grid = (OD/32, OD/8, (OD/8)*NBATCH).
// ---------------------------------------------------------------------------
__global__ __launch_bounds__(512) void sample_kernel(
        const float* __restrict__ vol, const float* __restrict__ theta,
        const float* __restrict__ fields, float* __restrict__ out) {
    __shared__ float e[3*ECH];   // 3*1088 floats = 13056 B

    const int tid  = threadIdx.x;
    const int lane = tid & 63;
    const int wl   = lane & 15;        // x within wave patch
    const int hl   = lane >> 4;        // y within wave patch (0..3)
    const int wv   = tid >> 6;         // wave id 0..7
    const int wx   = wv & 1;
    const int wh   = (wv >> 1) & 1;
    const int wd   = wv >> 2;          // 0..1

    const int ow_l = (wx << 4) | wl;       // 0..31
    const int oh_l = (wh << 2) | hl;       // 0..7
    const int ow   = (blockIdx.x << 5) | ow_l;
    const int oh   = (blockIdx.y << 3) | oh_l;
    const int odb  = (blockIdx.z & 15) << 3;   // od block base (0..120)
    const int n    = blockIdx.z >> 4;

    // ---- fill e: 3072 slots (xi in [0,16), real work xi<11), shifts only ----
    #pragma unroll
    for (int i = 0; i < 6; ++i) {
        const int t = tid + (i << 9);          // < 3072
        const int xi  = t & 15;
        const int row = t >> 4;                // 0..191 = c*64 + eoh*8 + eod
        if (xi < FSZ) {
            const int c   = row >> 6;
            const int r   = row & 63;
            const int eoh = r >> 3;
            const int eod = r & 7;
            int d_ = odb + eod + CROP0;
            int h_ = (blockIdx.y << 3) + eoh + CROP0;
            int zi0, zi1, yi0, yi1;
            float zw, yw;
            resize_coord(d_, zi0, zi1, zw);
            resize_coord(h_, yi0, yi1, yw);
            const float* f = fields + c * (FSZ*FSZ*FSZ);
            float v = f[zi0*121 + yi0*11 + xi] * ((1.0f-zw)*(1.0f-yw))
                    + f[zi0*121 + yi1*11 + xi] * ((1.0f-zw)*yw)
                    + f[zi1*121 + yi0*11 + xi] * (zw*(1.0f-yw))
                    + f[zi1*121 + yi1*11 + xi] * (zw*yw);
            e[row*ESTR + xi] = v * 80.0f;      // voxel units
        }
    }
    __syncthreads();

    const int w_ = ow + CROP0;
    const int h_ = oh + CROP0;

    const float x = fmaf(2.0f * (float)w_ + 1.0f, 1.0f / (float)VD, -1.0f);
    const float y = fmaf(2.0f * (float)h_ + 1.0f, 1.0f / (float)VD, -1.0f);

    // x-knot: s in [0.63, 9.38] for valid w_ -> xi0<=9, xi1=xi0+1 always
    float s = fmaf((float)w_ + 0.5f, (float)FSZ / (float)VD, -0.5f);
    s = fminf(fmaxf(s, 0.0f), (float)(FSZ - 1));
    const float sf = floorf(s);
    const int   xi0 = (int)sf;
    const float xw  = s - sf;

    const float* th = theta + n*12;
    const float cx = fmaf(th[0]*x + th[1]*y + th[3], 80.0f, 79.5f);
    const float cy = fmaf(th[4]*x + th[5]*y + th[7], 80.0f, 79.5f);
    const float cz = fmaf(th[8]*x + th[9]*y + th[11], 80.0f, 79.5f);
    const float tz0 = th[2] * 80.0f, tz1 = th[6] * 80.0f, tz2 = th[10] * 80.0f;

    const float* v = vol + (size_t)n * (VD*VD*VD);

    // single vaddr for all e reads; (c,k) parts are immediate offsets
    const float* ebase = &e[oh_l*EOH + (wd << 2)*ESTR + xi0];

    #pragma unroll
    for (int k = 0; k < ODQ; ++k) {
        const int od = odb + ((wd << 2) | k);
        const int d_ = od + CROP0;
        const float z = fmaf(2.0f * (float)d_ + 1.0f, 1.0f / (float)VD, -1.0f);

        const float ex0 = ebase[        k*ESTR    ], ex1 = ebase[        k*ESTR + 1];
        const float ey0 = ebase[ECH   + k*ESTR    ], ey1 = ebase[ECH   + k*ESTR + 1];
        const float ez0 = ebase[2*ECH + k*ESTR    ], ez1 = ebase[2*ECH + k*ESTR + 1];
        const float d80x = fmaf(ex1 - ex0, xw, ex0);
        const float d80y = fmaf(ey1 - ey0, xw, ey0);
        const float d80z = fmaf(ez1 - ez0, xw, ez0);

        const float xs = fmaf(tz0, z, cx) + d80x;
        const float ys = fmaf(tz1, z, cy) + d80y;
        const float zs = fmaf(tz2, z, cz) + d80z;

        const float x0f = floorf(xs), y0f = floorf(ys), z0f = floorf(zs);
        const float fx = xs - x0f, fy = ys - y0f, fz = zs - z0f;
        const int ix0 = (int)x0f, iy0 = (int)y0f, iz0 = (int)z0f;
        const int ix1 = ix0 + 1,  iy1 = iy0 + 1,  iz1 = iz0 + 1;

        const float WX0 = ((unsigned)ix0 < (unsigned)VD) ? (1.0f - fx) : 0.0f;
        const float WX1 = ((unsigned)ix1 < (unsigned)VD) ? fx          : 0.0f;
        const float WY0 = ((unsigned)iy0 < (unsigned)VD) ? (1.0f - fy) : 0.0f;
        const float WY1 = ((unsigned)iy1 < (unsigned)VD) ? fy          : 0.0f;
        const float WZ0 = ((unsigned)iz0 < (unsigned)VD) ? (1.0f - fz) : 0.0f;
        const float WZ1 = ((unsigned)iz1 < (unsigned)VD) ? fz          : 0.0f;

        const int xc0 = min(max(ix0, 0), VD-1), xc1 = min(max(ix1, 0), VD-1);
        const int yc0 = min(max(iy0, 0), VD-1), yc1 = min(max(iy1, 0), VD-1);
        const int zc0 = min(max(iz0, 0), VD-1), zc1 = min(max(iz1, 0), VD-1);

        // one dwordx2 covers both x-taps; fold x-selection into wA/wB
        const int base = min(xc0, VD-2);
        const bool hi0 = (xc0 != base);
        const bool hi1 = (xc1 != base);
        const float wA = (hi0 ? 0.0f : WX0) + (hi1 ? 0.0f : WX1);
        const float wB = (hi0 ? WX0 : 0.0f) + (hi1 ? WX1 : 0.0f);

        const int b00 = (zc0*VD + yc0)*VD + base;
        const int b01 = (zc0*VD + yc1)*VD + base;
        const int b10 = (zc1*VD + yc0)*VD + base;
        const int b11 = (zc1*VD + yc1)*VD + base;

        float2 p00, p01, p10, p11;
        __builtin_memcpy(&p00, v + b00, sizeof(float2));
        __builtin_memcpy(&p01, v + b01, sizeof(float2));
        __builtin_memcpy(&p10, v + b10, sizeof(float2));
        __builtin_memcpy(&p11, v + b11, sizeof(float2));

        const float r00 = p00.x*wA + p00.y*wB;
        const float r01 = p01.x*wA + p01.y*wB;
        const float r10 = p10.x*wA + p10.y*wB;
        const float r11 = p11.x*wA + p11.y*wB;
        const float r = (r00*WY0 + r01*WY1)*WZ0 + (r10*WY0 + r11*WY1)*WZ1;

        out[(((size_t)n*OD + od)*OD + oh)*OD + ow] = r;
    }
}

// ---------------------------------------------------------------------------
extern "C" void kernel_launch(void* const* d_in, const int* in_sizes, int n_in,
                              void* d_out, int out_size, void* d_ws, size_t ws_size,
                              hipStream_t stream) {
    const float* vol   = (const float*)d_in[0];
    const float* rot   = (const float*)d_in[1];
    const float* scale = (const float*)d_in[2];
    const float* shift = (const float*)d_in[3];
    const float* dz    = (const float*)d_in[4];
    const float* dy    = (const float*)d_in[5];
    const float* dx    = (const float*)d_in[6];
    float* out = (float*)d_out;

    float* ws     = (float*)d_ws;
    float* theta  = ws;         // 4*12 = 48 floats
    float* fields = ws + 48;    // 3*1331 floats

    prep_kernel<<<4, 256, 0, stream>>>(rot, scale, shift, dz, dy, dx,
                                       theta, fields);
    dim3 grid(OD/32, OD/8, (OD/8)*NBATCH);
    sample_kernel<<<grid, 512, 0, stream>>>(vol, theta, fields, out);
}